// Round 5
// baseline (1301.941 us; speedup 1.0000x reference)
//
#include <hip/hip_runtime.h>
#include <math.h>

#define DIMC 256
#define CO   516
#define NB   32
#define NH   64
#define NW   64
#define NPIX (NB*NH*NW)   // 131072
#define PITCH 264         // GEMM LDS row pitch in shorts (256 + 8 pad)
#define PX    32          // pixels per GEMM block (32 -> 33.8KB LDS, 4 blocks/CU)
#define CP    76          // conv LDS pitch (floats)
#define CROWS 72          // 64 + 2*4 halo

typedef short short8 __attribute__((ext_vector_type(8)));
typedef float floatx4 __attribute__((ext_vector_type(4)));
typedef unsigned short us4 __attribute__((ext_vector_type(4)));

__device__ __forceinline__ float gelu_f(float x) {
    return 0.5f * x * (1.0f + erff(x * 0.7071067811865476f));
}
__device__ __forceinline__ float clip100(float v) {
    return fminf(100.f, fmaxf(-100.f, v));
}
// round-to-nearest-even split of fp32 into bf16 hi + bf16 lo (x ~= hi+lo)
__device__ __forceinline__ void split2(float x, unsigned short& h, unsigned short& l) {
    unsigned int xb = __float_as_uint(x);
    unsigned int hb = (xb + 0x7fffu + ((xb >> 16) & 1u)) & 0xffff0000u;
    h = (unsigned short)(hb >> 16);
    float r = x - __uint_as_float(hb);
    unsigned int rb = __float_as_uint(r);
    l = (unsigned short)((rb + 0x7fffu + ((rb >> 16) & 1u)) >> 16);
}
__device__ __forceinline__ float bf2f(unsigned short h) {
    return __uint_as_float(((unsigned int)h) << 16);
}

// ---------------------------------------------------------------------------
// Weight prep: transpose + split to bf16 hi/lo.
//   wiT rows 0..515 (incl. gate cols 512..515!), wmT, wpT.
// Grid 1028 blocks x 256 threads (t = k).
// ---------------------------------------------------------------------------
__global__ __launch_bounds__(256) void k_prep(const float* __restrict__ w_init,
                                              const float* __restrict__ w_mod,
                                              const float* __restrict__ w_proj,
                                              unsigned short* wiT_h, unsigned short* wiT_l,
                                              unsigned short* wmT_h, unsigned short* wmT_l,
                                              unsigned short* wpT_h, unsigned short* wpT_l) {
    const int n = blockIdx.x;
    const int k = threadIdx.x;
    unsigned short h, l;
    if (n < 516) {
        split2(w_init[k * CO + n], h, l);
        wiT_h[n * 256 + k] = h; wiT_l[n * 256 + k] = l;
    } else if (n < 772) {
        const int nn = n - 516;
        split2(w_mod[k * 256 + nn], h, l);
        wmT_h[nn * 256 + k] = h; wmT_l[nn * 256 + k] = l;
    } else {
        const int nn = n - 772;
        split2(w_proj[k * 256 + nn], h, l);
        wpT_h[nn * 256 + k] = h; wpT_l[nn * 256 + k] = l;
    }
}

// ---------------------------------------------------------------------------
// k_init_mfma: x_proj = x @ w_init + b_init (split-bf16 MFMA), 32-pixel tile.
//   q (cols 0..255)    -> qout [pix][c]  (aliases d_out)
//   ctx (cols 256..511)-> ctxp PLANAR [b][c][4096]
//   gates (512..515)   -> gates [pix][4], clipped (from transposed wiT rows)
// 4 waves; per half each wave owns 64 cols (2m x 4n 16x16 tiles).
// ---------------------------------------------------------------------------
__global__ __launch_bounds__(256, 4) void k_init_mfma(const float* __restrict__ x,
                                                      const unsigned short* __restrict__ wiT_h,
                                                      const unsigned short* __restrict__ wiT_l,
                                                      const float* __restrict__ b_init,
                                                      float* __restrict__ qout,
                                                      float* __restrict__ ctxp,
                                                      float* __restrict__ gates) {
    __shared__ unsigned short Ah[PX * PITCH];
    __shared__ unsigned short Al[PX * PITCH];
    const int t = threadIdx.x;
    const long p0 = (long)blockIdx.x * PX;
    const int bb = (int)(p0 >> 12);
    const int pl = (int)(p0 & 4095);

    // stage x tile (32x256 fp32) -> hi/lo bf16 LDS
    #pragma unroll
    for (int i = 0; i < 8; ++i) {
        const int idx = i * 256 + t;
        const int row = idx >> 6, c4 = idx & 63;
        const float4 v = ((const float4*)x)[(p0 + row) * 64 + c4];
        unsigned short h0,h1,h2,h3,l0,l1,l2,l3;
        split2(v.x,h0,l0); split2(v.y,h1,l1); split2(v.z,h2,l2); split2(v.w,h3,l3);
        *(us4*)&Ah[row * PITCH + c4 * 4] = (us4){h0,h1,h2,h3};
        *(us4*)&Al[row * PITCH + c4 * 4] = (us4){l0,l1,l2,l3};
    }
    __syncthreads();

    const int wv = t >> 6, lane = t & 63;
    const int l15 = lane & 15, quad = lane >> 4;

    for (int half = 0; half < 2; ++half) {
        const int ncol0 = half * 256 + wv * 64;
        floatx4 acc[2][4];
        #pragma unroll
        for (int im = 0; im < 2; ++im)
            #pragma unroll
            for (int in_ = 0; in_ < 4; ++in_)
                acc[im][in_] = (floatx4){0.f, 0.f, 0.f, 0.f};

        for (int kk = 0; kk < 256; kk += 32) {
            short8 ah[2], al[2], bh[4], bl[4];
            #pragma unroll
            for (int im = 0; im < 2; ++im) {
                const int off = (im * 16 + l15) * PITCH + kk + quad * 8;
                ah[im] = *(const short8*)&Ah[off];
                al[im] = *(const short8*)&Al[off];
            }
            #pragma unroll
            for (int in_ = 0; in_ < 4; ++in_) {
                const int n = ncol0 + in_ * 16 + l15;
                const int off = n * 256 + kk + quad * 8;
                bh[in_] = *(const short8*)&wiT_h[off];
                bl[in_] = *(const short8*)&wiT_l[off];
            }
            #pragma unroll
            for (int im = 0; im < 2; ++im)
                #pragma unroll
                for (int in_ = 0; in_ < 4; ++in_) {
                    acc[im][in_] = __builtin_amdgcn_mfma_f32_16x16x32_bf16(ah[im], bh[in_], acc[im][in_], 0, 0, 0);
                    acc[im][in_] = __builtin_amdgcn_mfma_f32_16x16x32_bf16(ah[im], bl[in_], acc[im][in_], 0, 0, 0);
                    acc[im][in_] = __builtin_amdgcn_mfma_f32_16x16x32_bf16(al[im], bh[in_], acc[im][in_], 0, 0, 0);
                }
        }

        if (half == 0) {
            #pragma unroll
            for (int in_ = 0; in_ < 4; ++in_) {
                const int col = wv * 64 + in_ * 16 + l15;
                const float bi = b_init[col];
                #pragma unroll
                for (int im = 0; im < 2; ++im)
                    #pragma unroll
                    for (int r = 0; r < 4; ++r) {
                        const int row = im * 16 + quad * 4 + r;
                        qout[(p0 + row) * 256 + col] = acc[im][in_][r] + bi;
                    }
            }
        } else {
            #pragma unroll
            for (int in_ = 0; in_ < 4; ++in_) {
                const int col = wv * 64 + in_ * 16 + l15;     // channel
                const float bi = b_init[256 + col];
                #pragma unroll
                for (int im = 0; im < 2; ++im) {
                    float4 o;
                    o.x = acc[im][in_][0] + bi;
                    o.y = acc[im][in_][1] + bi;
                    o.z = acc[im][in_][2] + bi;
                    o.w = acc[im][in_][3] + bi;
                    *(float4*)&ctxp[((size_t)bb * 256 + col) * 4096 + pl + im * 16 + quad * 4] = o;
                }
            }
        }
    }

    // gates epilogue: threads 0..127 -> pixel p=t>>2, gate col=t&3.
    // Weights from transposed wiT rows 512..515 (contiguous, broadcast loads).
    if (t < 4 * PX) {
        const int p = t >> 2, col = t & 3;
        float g = b_init[512 + col];
        const unsigned short* wh = &wiT_h[(512 + col) * 256];
        const unsigned short* wl = &wiT_l[(512 + col) * 256];
        for (int k = 0; k < 256; k += 8) {
            const short8 xh = *(const short8*)&Ah[p * PITCH + k];
            const short8 xl = *(const short8*)&Al[p * PITCH + k];
            const short8 vh = *(const short8*)&wh[k];
            const short8 vl = *(const short8*)&wl[k];
            #pragma unroll
            for (int j = 0; j < 8; ++j) {
                const float xf = bf2f((unsigned short)xh[j]) + bf2f((unsigned short)xl[j]);
                const float wf = bf2f((unsigned short)vh[j]) + bf2f((unsigned short)vl[j]);
                g = fmaf(xf, wf, g);
            }
        }
        g = fminf(1.f, fmaxf(-1.f, g));
        gates[(p0 + p) * 4 + col] = g;
    }
}

// ---------------------------------------------------------------------------
// conv_level: 4x4 output patch from LDS plane I (halo 4, pitch CP).
// ---------------------------------------------------------------------------
template<int KS>
__device__ __forceinline__ void conv_level(const float* __restrict__ kwp,
                                           const float* __restrict__ I,
                                           int ry0, int cx0, float v[16]) {
    constexpr int P = KS / 2;
    constexpr int RWIN = 4 + 2 * P;
    float wk[KS * KS];
    #pragma unroll
    for (int i = 0; i < KS * KS; ++i) wk[i] = kwp[i * 256];

    float4 rb[RWIN][3];
    #pragma unroll
    for (int r = 0; r < 2 * P; ++r) {
        const int base = (ry0 + r - P + 4) * CP + cx0;
        rb[r][0] = *(const float4*)&I[base];
        rb[r][1] = *(const float4*)&I[base + 4];
        rb[r][2] = *(const float4*)&I[base + 8];
    }
    #pragma unroll
    for (int j = 0; j < 4; ++j) {
        {
            const int r = j + 2 * P;
            const int base = (ry0 + r - P + 4) * CP + cx0;
            rb[r][0] = *(const float4*)&I[base];
            rb[r][1] = *(const float4*)&I[base + 4];
            rb[r][2] = *(const float4*)&I[base + 8];
        }
        float s0 = 0.f, s1 = 0.f, s2 = 0.f, s3 = 0.f;
        #pragma unroll
        for (int dy = 0; dy < KS; ++dy) {
            const float* rw = (const float*)&rb[j + dy][0];
            #pragma unroll
            for (int dx = 0; dx < KS; ++dx) {
                const float wgt = wk[dy * KS + dx];
                s0 += rw[4 - P + 0 + dx] * wgt;
                s1 += rw[4 - P + 1 + dx] * wgt;
                s2 += rw[4 - P + 2 + dx] * wgt;
                s3 += rw[4 - P + 3 + dx] * wgt;
            }
        }
        v[j * 4 + 0] = gelu_f(s0);
        v[j * 4 + 1] = gelu_f(s1);
        v[j * 4 + 2] = gelu_f(s2);
        v[j * 4 + 3] = gelu_f(s3);
    }
}

// ---------------------------------------------------------------------------
// k_conv_fused: one block per (b,c) plane; full conv chain + gating + in-block
// global mean in LDS. (unchanged from R4)
// ---------------------------------------------------------------------------
__global__ __launch_bounds__(256) void k_conv_fused(const float* __restrict__ ctxp,
                                                    const float* __restrict__ k0,
                                                    const float* __restrict__ k1,
                                                    const float* __restrict__ k2,
                                                    const float* __restrict__ gates,
                                                    float* __restrict__ c_allp) {
    __shared__ float X[CROWS * CP];
    __shared__ float Y[CROWS * CP];
    const int t = threadIdx.x;
    const int bc = blockIdx.x;
    const int b = bc >> 8, c = bc & 255;
    const float* src = ctxp + (size_t)bc * 4096;

    for (int i = t; i < CROWS * CP; i += 256) { X[i] = 0.f; Y[i] = 0.f; }
    __syncthreads();
    #pragma unroll
    for (int i = 0; i < 4; ++i) {
        const int p = i * 1024 + t * 4;
        const float4 vv = *(const float4*)&src[p];
        *(float4*)&X[((p >> 6) + 4) * CP + (p & 63) + 4] = vv;
    }
    __syncthreads();

    const int px = t & 15, py = t >> 4;
    const int cx0 = px * 4, ry0 = py * 4;
    const float* gbase = gates + (size_t)b * 4096 * 4;

    float acc[16], v[16];

    conv_level<3>(k0 + c, X, ry0, cx0, v);
    #pragma unroll
    for (int j = 0; j < 4; ++j) {
        *(float4*)&Y[(ry0 + j + 4) * CP + cx0 + 4] = *(float4*)&v[j * 4];
        #pragma unroll
        for (int i2 = 0; i2 < 4; ++i2)
            acc[j * 4 + i2] = v[j * 4 + i2] * gbase[((ry0 + j) * 64 + cx0 + i2) * 4 + 0];
    }
    __syncthreads();

    conv_level<5>(k1 + c, Y, ry0, cx0, v);
    #pragma unroll
    for (int j = 0; j < 4; ++j) {
        *(float4*)&X[(ry0 + j + 4) * CP + cx0 + 4] = *(float4*)&v[j * 4];
        #pragma unroll
        for (int i2 = 0; i2 < 4; ++i2)
            acc[j * 4 + i2] += v[j * 4 + i2] * gbase[((ry0 + j) * 64 + cx0 + i2) * 4 + 1];
    }
    __syncthreads();

    conv_level<7>(k2 + c, X, ry0, cx0, v);
    float vsum = 0.f;
    #pragma unroll
    for (int j = 0; j < 4; ++j)
        #pragma unroll
        for (int i2 = 0; i2 < 4; ++i2) {
            acc[j * 4 + i2] += v[j * 4 + i2] * gbase[((ry0 + j) * 64 + cx0 + i2) * 4 + 2];
            vsum += v[j * 4 + i2];
        }

    __syncthreads();
    X[t] = vsum;
    __syncthreads();
    if (t < 64) {
        float s = X[t] + X[t + 64] + X[t + 128] + X[t + 192];
        #pragma unroll
        for (int off = 32; off >= 1; off >>= 1)
            s += __shfl_down(s, off, 64);
        if (t == 0) X[0] = tanhf(s * (1.f / 4096.f));
    }
    __syncthreads();
    const float gl = X[0];

    float* dst = c_allp + (size_t)bc * 4096;
    #pragma unroll
    for (int j = 0; j < 4; ++j) {
        float4 o;
        o.x = acc[j * 4 + 0] + gl * gbase[((ry0 + j) * 64 + cx0 + 0) * 4 + 3];
        o.y = acc[j * 4 + 1] + gl * gbase[((ry0 + j) * 64 + cx0 + 1) * 4 + 3];
        o.z = acc[j * 4 + 2] + gl * gbase[((ry0 + j) * 64 + cx0 + 2) * 4 + 3];
        o.w = acc[j * 4 + 3] + gl * gbase[((ry0 + j) * 64 + cx0 + 3) * 4 + 3];
        *(float4*)&dst[(ry0 + j) * 64 + cx0] = o;
    }
}

// ---------------------------------------------------------------------------
// k_final_mfma: 32-pixel tile. Stage c_allp (planar->LDS transpose, split);
// GEMM1 mod; p = clip(q)*clip(mod+b_mod); GEMM2 out = p@w_proj + b_proj.
// qout aliases d_out (holds q on entry).
// ---------------------------------------------------------------------------
__global__ __launch_bounds__(256, 4) void k_final_mfma(float* qout,
                                                       const float* __restrict__ c_allp,
                                                       const unsigned short* __restrict__ wmT_h,
                                                       const unsigned short* __restrict__ wmT_l,
                                                       const unsigned short* __restrict__ wpT_h,
                                                       const unsigned short* __restrict__ wpT_l,
                                                       const float* __restrict__ b_mod,
                                                       const float* __restrict__ b_proj) {
    __shared__ unsigned short Ah[PX * PITCH];
    __shared__ unsigned short Al[PX * PITCH];
    const int t = threadIdx.x;
    const long p0 = (long)blockIdx.x * PX;
    const int b = (int)(p0 >> 12);
    const int pl = (int)(p0 & 4095);

    // transpose-stage: thread t = channel t, 32 consecutive pixels
    {
        const float* src = c_allp + ((size_t)b * 256 + t) * 4096 + pl;
        #pragma unroll
        for (int i = 0; i < 8; ++i) {
            const float4 vv = *(const float4*)&src[i * 4];
            unsigned short h, l;
            split2(vv.x, h, l); Ah[(i*4+0)*PITCH + t] = h; Al[(i*4+0)*PITCH + t] = l;
            split2(vv.y, h, l); Ah[(i*4+1)*PITCH + t] = h; Al[(i*4+1)*PITCH + t] = l;
            split2(vv.z, h, l); Ah[(i*4+2)*PITCH + t] = h; Al[(i*4+2)*PITCH + t] = l;
            split2(vv.w, h, l); Ah[(i*4+3)*PITCH + t] = h; Al[(i*4+3)*PITCH + t] = l;
        }
    }
    __syncthreads();

    const int wv = t >> 6, lane = t & 63;
    const int l15 = lane & 15, quad = lane >> 4;
    const int ncol0 = wv * 64;

    floatx4 acc[2][4];
    #pragma unroll
    for (int im = 0; im < 2; ++im)
        #pragma unroll
        for (int in_ = 0; in_ < 4; ++in_)
            acc[im][in_] = (floatx4){0.f, 0.f, 0.f, 0.f};

    // GEMM1: mod = c_all @ w_mod
    for (int kk = 0; kk < 256; kk += 32) {
        short8 ah[2], al[2], bh[4], bl[4];
        #pragma unroll
        for (int im = 0; im < 2; ++im) {
            const int off = (im * 16 + l15) * PITCH + kk + quad * 8;
            ah[im] = *(const short8*)&Ah[off];
            al[im] = *(const short8*)&Al[off];
        }
        #pragma unroll
        for (int in_ = 0; in_ < 4; ++in_) {
            const int off = (ncol0 + in_ * 16 + l15) * 256 + kk + quad * 8;
            bh[in_] = *(const short8*)&wmT_h[off];
            bl[in_] = *(const short8*)&wmT_l[off];
        }
        #pragma unroll
        for (int im = 0; im < 2; ++im)
            #pragma unroll
            for (int in_ = 0; in_ < 4; ++in_) {
                acc[im][in_] = __builtin_amdgcn_mfma_f32_16x16x32_bf16(ah[im], bh[in_], acc[im][in_], 0, 0, 0);
                acc[im][in_] = __builtin_amdgcn_mfma_f32_16x16x32_bf16(ah[im], bl[in_], acc[im][in_], 0, 0, 0);
                acc[im][in_] = __builtin_amdgcn_mfma_f32_16x16x32_bf16(al[im], bh[in_], acc[im][in_], 0, 0, 0);
            }
    }
    __syncthreads();

    // epilogue1: p = clip(q)*clip(mod + b_mod) -> LDS hi/lo
    #pragma unroll
    for (int in_ = 0; in_ < 4; ++in_) {
        const int col = ncol0 + in_ * 16 + l15;
        const float bm = b_mod[col];
        #pragma unroll
        for (int im = 0; im < 2; ++im)
            #pragma unroll
            for (int r = 0; r < 4; ++r) {
                const int row = im * 16 + quad * 4 + r;
                const float m = clip100(acc[im][in_][r] + bm);
                const float qv = clip100(qout[(p0 + row) * 256 + col]);
                unsigned short h, l;
                split2(qv * m, h, l);
                Ah[row * PITCH + col] = h;
                Al[row * PITCH + col] = l;
            }
    }
    __syncthreads();

    // GEMM2: out = p @ w_proj
    #pragma unroll
    for (int im = 0; im < 2; ++im)
        #pragma unroll
        for (int in_ = 0; in_ < 4; ++in_)
            acc[im][in_] = (floatx4){0.f, 0.f, 0.f, 0.f};

    for (int kk = 0; kk < 256; kk += 32) {
        short8 ah[2], al[2], bh[4], bl[4];
        #pragma unroll
        for (int im = 0; im < 2; ++im) {
            const int off = (im * 16 + l15) * PITCH + kk + quad * 8;
            ah[im] = *(const short8*)&Ah[off];
            al[im] = *(const short8*)&Al[off];
        }
        #pragma unroll
        for (int in_ = 0; in_ < 4; ++in_) {
            const int off = (ncol0 + in_ * 16 + l15) * 256 + kk + quad * 8;
            bh[in_] = *(const short8*)&wpT_h[off];
            bl[in_] = *(const short8*)&wpT_l[off];
        }
        #pragma unroll
        for (int im = 0; im < 2; ++im)
            #pragma unroll
            for (int in_ = 0; in_ < 4; ++in_) {
                acc[im][in_] = __builtin_amdgcn_mfma_f32_16x16x32_bf16(ah[im], bh[in_], acc[im][in_], 0, 0, 0);
                acc[im][in_] = __builtin_amdgcn_mfma_f32_16x16x32_bf16(ah[im], bl[in_], acc[im][in_], 0, 0, 0);
                acc[im][in_] = __builtin_amdgcn_mfma_f32_16x16x32_bf16(al[im], bh[in_], acc[im][in_], 0, 0, 0);
            }
    }

    #pragma unroll
    for (int in_ = 0; in_ < 4; ++in_) {
        const int col = ncol0 + in_ * 16 + l15;
        const float bp = b_proj[col];
        #pragma unroll
        for (int im = 0; im < 2; ++im)
            #pragma unroll
            for (int r = 0; r < 4; ++r) {
                const int row = im * 16 + quad * 4 + r;
                qout[(p0 + row) * 256 + col] = acc[im][in_][r] + bp;
            }
    }
}

// ---------------------------------------------------------------------------
extern "C" void kernel_launch(void* const* d_in, const int* in_sizes, int n_in,
                              void* d_out, int out_size, void* d_ws, size_t ws_size,
                              hipStream_t stream) {
    const float* x      = (const float*)d_in[0];
    const float* w_init = (const float*)d_in[1];
    const float* b_init = (const float*)d_in[2];
    const float* k0     = (const float*)d_in[3];
    const float* k1     = (const float*)d_in[4];
    const float* k2     = (const float*)d_in[5];
    const float* w_mod  = (const float*)d_in[6];
    const float* b_mod  = (const float*)d_in[7];
    const float* w_proj = (const float*)d_in[8];
    const float* b_proj = (const float*)d_in[9];
    float* qout = (float*)d_out;

    float* ws = (float*)d_ws;
    const long NP = (long)NPIX * DIMC;
    float* ctxp    = ws;                          // planar [b][c][4096]
    float* c_allp  = ws + NP;                     // planar [b][c][4096]
    float* gates   = ws + 2 * NP;                 // NPIX*4 floats
    unsigned short* wiT_h = (unsigned short*)(gates + (long)NPIX * 4);
    unsigned short* wiT_l = wiT_h + 516 * 256;
    unsigned short* wmT_h = wiT_l + 516 * 256;
    unsigned short* wmT_l = wmT_h + 256 * 256;
    unsigned short* wpT_h = wmT_l + 256 * 256;
    unsigned short* wpT_l = wpT_h + 256 * 256;

    k_prep<<<1028, 256, 0, stream>>>(w_init, w_mod, w_proj,
                                     wiT_h, wiT_l, wmT_h, wmT_l, wpT_h, wpT_l);
    k_init_mfma<<<NPIX / PX, 256, 0, stream>>>(x, wiT_h, wiT_l, b_init,
                                               qout, ctxp, gates);
    k_conv_fused<<<NB * 256, 256, 0, stream>>>(ctxp, k0, k1, k2, gates, c_allp);
    k_final_mfma<<<NPIX / PX, 256, 0, stream>>>(qout, c_allp,
                                                wmT_h, wmT_l, wpT_h, wpT_l,
                                                b_mod, b_proj);
}